// Round 2
// baseline (139.533 us; speedup 1.0000x reference)
//
#include <hip/hip_runtime.h>
#include <stdint.h>

// ---- problem dims ----
#define NROWS 8192
#define LDIM  1024
#define HDIM  512
#define DDIM  256

typedef __attribute__((ext_vector_type(8))) short short8;
typedef __attribute__((ext_vector_type(4))) float f32x4;
typedef __attribute__((ext_vector_type(4))) unsigned int u32x4;

typedef __attribute__((address_space(3))) unsigned int lds_uint;
typedef const __attribute__((address_space(1))) unsigned int glob_uint;

__device__ __forceinline__ void llds16(const void* g, void* l) {
  __builtin_amdgcn_global_load_lds((glob_uint*)g, (lds_uint*)l, 16, 0, 0);
}

__device__ __forceinline__ unsigned short f2bf(float f) {
  union { float f; unsigned int u; } c; c.f = f;
  unsigned int u = c.u;
  unsigned int r = (u + 0x7fffu + ((u >> 16) & 1u)) >> 16;
  return (unsigned short)r;
}

__device__ __forceinline__ float bfbits2f(unsigned int hi16) {
  union { unsigned int u; float f; } c; c.u = hi16;
  return c.f;
}

// ---- zero the 268MB output with 16B nontemporal stores ----
__global__ __launch_bounds__(256) void zero_out_kernel(float* __restrict__ out) {
  const long total16 = 16777216;  // uint4 chunks covering floats [0, 67108864)
  long idx = (long)blockIdx.x * 256 + threadIdx.x;
  u32x4 z = {0u, 0u, 0u, 0u};
  u32x4* p = (u32x4*)out;
  const long stride = (long)gridDim.x * 256;
  for (long i = idx; i < total16; i += stride)
    __builtin_nontemporal_store(z, p + i);
  if (idx == 0) { out[67108864] = 0.f; out[67108865] = 0.f; }
}

// ---- x f32 -> bf16, 8 elems/thread ----
__global__ __launch_bounds__(256) void conv_x_kernel(const float* __restrict__ x,
                                                     unsigned short* __restrict__ xb) {
  long i = ((long)blockIdx.x * 256 + threadIdx.x) * 8;
  float4 v0 = *(const float4*)(x + i);
  float4 v1 = *(const float4*)(x + i + 4);
  union { unsigned short s[8]; uint4 u; } o;
  o.s[0] = f2bf(v0.x); o.s[1] = f2bf(v0.y); o.s[2] = f2bf(v0.z); o.s[3] = f2bf(v0.w);
  o.s[4] = f2bf(v1.x); o.s[5] = f2bf(v1.y); o.s[6] = f2bf(v1.z); o.s[7] = f2bf(v1.w);
  *(uint4*)(xb + i) = o.u;
}

// ---- weights: transpose + convert. WfcT[512][1024], WabT[512][512] (Wa^T rows 0..255, Wb^T rows 256..511 stacked along n) ----
__global__ __launch_bounds__(256) void prep_w_kernel(const float* __restrict__ Wfc,
                                                     const float* __restrict__ Wa,
                                                     const float* __restrict__ Wb,
                                                     unsigned short* __restrict__ WfcT,
                                                     unsigned short* __restrict__ WabT) {
  int idx = blockIdx.x * 256 + threadIdx.x;  // 0 .. 786431
  if (idx < 512 * 1024) {
    int n = idx >> 10, k = idx & 1023;
    WfcT[idx] = f2bf(Wfc[k * 512 + n]);
  } else {
    int j = idx - 512 * 1024;
    int n = j >> 9, k = j & 511;
    float v = (n < 256) ? Wa[k * 256 + n] : Wb[k * 256 + (n - 256)];
    WabT[j] = f2bf(v);
  }
}

// ---- bf16 GEMM, A[M][K] x Bt[N][K] -> out[M][N]. EPI 0: relu(acc+bias)->bf16 ; EPI 1: raw f32 ----
template <int EPI>
__global__ __launch_bounds__(256) void gemm_bt(const unsigned short* __restrict__ A,
                                               const unsigned short* __restrict__ Bt,
                                               const float* __restrict__ bias,
                                               void* __restrict__ out,
                                               int M, int N, int K) {
  constexpr int BM = 128, BN = 64, BK = 32;
  __shared__ unsigned short sA[2][BM * BK];
  __shared__ unsigned short sB[2][BN * BK];
  const int tid = threadIdx.x;
  const int lane = tid & 63;
  const int wv = tid >> 6;        // wave 0..3
  const int wm = wv >> 1;         // row half
  const int wn = wv & 1;          // col half
  const int nbn = N / BN;
  const int bm = blockIdx.x / nbn, bn = blockIdx.x % nbn;
  const int row0 = bm * BM, col0 = bn * BN;

  f32x4 acc[4][2] = {};
  const int nk = K / BK;

  auto stage = [&](int buf, int kt) {
    // A tile: 128x32 shorts = 512 16B-chunks, 2 rounds
#pragma unroll
    for (int r = 0; r < 2; ++r) {
      int c = r * 256 + tid;
      int arow = c >> 2, acb = (c & 3) * 8;
      const unsigned short* g = A + (long)(row0 + arow) * K + kt * BK + acb;
      unsigned short* l = (unsigned short*)&sA[buf][(r * 256 + wv * 64) * 8];
      llds16(g, l);
    }
    // B tile: 64x32 shorts = 256 chunks, 1 round
    {
      int c = tid;
      int brow = c >> 2, bcb = (c & 3) * 8;
      const unsigned short* g = Bt + (long)(col0 + brow) * K + kt * BK + bcb;
      unsigned short* l = (unsigned short*)&sB[buf][(wv * 64) * 8];
      llds16(g, l);
    }
  };

  stage(0, 0);
  __syncthreads();

  for (int kt = 0; kt < nk; ++kt) {
    int cur = kt & 1;
    if (kt + 1 < nk) stage(cur ^ 1, kt + 1);
    const unsigned short* bA = sA[cur];
    const unsigned short* bB = sB[cur];
    short8 af[4], bfr[2];
#pragma unroll
    for (int fm = 0; fm < 4; ++fm)
      af[fm] = *(const short8*)&bA[(wm * 64 + fm * 16 + (lane & 15)) * BK + (lane >> 4) * 8];
#pragma unroll
    for (int fn = 0; fn < 2; ++fn)
      bfr[fn] = *(const short8*)&bB[(wn * 32 + fn * 16 + (lane & 15)) * BK + (lane >> 4) * 8];
#pragma unroll
    for (int fm = 0; fm < 4; ++fm)
#pragma unroll
      for (int fn = 0; fn < 2; ++fn)
        acc[fm][fn] = __builtin_amdgcn_mfma_f32_16x16x32_bf16(af[fm], bfr[fn], acc[fm][fn], 0, 0, 0);
    __syncthreads();
  }

#pragma unroll
  for (int fm = 0; fm < 4; ++fm) {
#pragma unroll
    for (int fn = 0; fn < 2; ++fn) {
#pragma unroll
      for (int i = 0; i < 4; ++i) {
        int row = row0 + wm * 64 + fm * 16 + (lane >> 4) * 4 + i;
        int col = col0 + wn * 32 + fn * 16 + (lane & 15);
        float v = acc[fm][fn][i];
        if (EPI == 0) {
          v += bias[col];
          v = v > 0.f ? v : 0.f;
          ((unsigned short*)out)[(long)row * N + col] = f2bf(v);
        } else {
          ((float*)out)[(long)row * N + col] = v;
        }
      }
    }
  }
}

// ---- per-row score: s_i = sum_d tanh(t[i][d]+ba[d])*sigmoid(t[i][d+256]+bb[d])*Wc[d] + bc ----
__global__ __launch_bounds__(256) void score_kernel(const float* __restrict__ t,
                                                    const float* __restrict__ ba,
                                                    const float* __restrict__ bb,
                                                    const float* __restrict__ Wc,
                                                    const float* __restrict__ bc,
                                                    float* __restrict__ scores,
                                                    float* __restrict__ out /* d_out base */) {
  int row = blockIdx.x * 4 + (threadIdx.x >> 6);
  int lane = threadIdx.x & 63;
  const float* tr = t + (long)row * 512;
  float s = 0.f;
#pragma unroll
  for (int j = 0; j < 4; ++j) {
    int d = lane + j * 64;
    float u = tr[d] + ba[d];
    float v = tr[d + 256] + bb[d];
    float av = tanhf(u);
    float bv = 1.f / (1.f + __expf(-v));
    s += av * bv * Wc[d];
  }
#pragma unroll
  for (int off = 32; off; off >>= 1) s += __shfl_down(s, off);
  if (lane == 0) {
    float sc = s + bc[0];
    scores[row] = sc;
    out[2 + (long)row * 8193] = sc;  // A_raw diagonal (A_raw starts at flat offset 2)
  }
}

// ---- single-block: m, Z, then w_i = e_i/Z + (n-1)*e0/Z ----
__global__ __launch_bounds__(1024) void reduce_kernel(const float* __restrict__ scores,
                                                      float* __restrict__ w) {
  __shared__ float red[1024];
  int t = threadIdx.x;
  float v[8];
  float mx = -1e30f;
#pragma unroll
  for (int j = 0; j < 8; ++j) { v[j] = scores[t * 8 + j]; mx = fmaxf(mx, v[j]); }
  red[t] = mx; __syncthreads();
  for (int s = 512; s; s >>= 1) { if (t < s) red[t] = fmaxf(red[t], red[t + s]); __syncthreads(); }
  float m = fmaxf(red[0], 0.f);
  __syncthreads();
  float e[8]; float se = 0.f;
#pragma unroll
  for (int j = 0; j < 8; ++j) { e[j] = __expf(v[j] - m); se += e[j]; }
  red[t] = se; __syncthreads();
  for (int s = 512; s; s >>= 1) { if (t < s) red[t] += red[t + s]; __syncthreads(); }
  float e0 = __expf(-m);
  float Z = red[0] + 67100672.0f * e0;  // (n*n - n) * e0
  float c0 = 8191.0f * e0 / Z;          // (n-1)*e0/Z
#pragma unroll
  for (int j = 0; j < 8; ++j) w[t * 8 + j] = e[j] / Z + c0;
}

// ---- partial weighted colsum: part[b][j] = sum_{i in block b} w_i * h[i][j] ----
__global__ __launch_bounds__(256) void wsum_kernel(const unsigned short* __restrict__ h,
                                                   const float* __restrict__ w,
                                                   float* __restrict__ part) {
  int b = blockIdx.x;   // 64 blocks, 128 rows each
  int t = threadIdx.x;  // 256 threads, 2 cols each
  float a0 = 0.f, a1 = 0.f;
  for (int i = b * 128; i < b * 128 + 128; ++i) {
    float wi = w[i];
    unsigned int hv = *(const unsigned int*)&h[(long)i * 512 + t * 2];
    a0 += wi * bfbits2f(hv << 16);
    a1 += wi * bfbits2f(hv & 0xffff0000u);
  }
  part[b * 512 + t * 2] = a0;
  part[b * 512 + t * 2 + 1] = a1;
}

// ---- M[j] = sum_b part[b][j]; logits = M @ Wcls + bcls ----
__global__ __launch_bounds__(512) void final_kernel(const float* __restrict__ part,
                                                    const float* __restrict__ Wcls,
                                                    const float* __restrict__ bcls,
                                                    float* __restrict__ out) {
  __shared__ float Msh[512];
  int t = threadIdx.x;
  float s = 0.f;
  for (int b = 0; b < 64; ++b) s += part[b * 512 + t];
  Msh[t] = s;
  __syncthreads();
  if (t < 64) {
    float p0 = 0.f, p1 = 0.f;
    for (int j = t; j < 512; j += 64) { p0 += Msh[j] * Wcls[j * 2]; p1 += Msh[j] * Wcls[j * 2 + 1]; }
#pragma unroll
    for (int off = 32; off; off >>= 1) { p0 += __shfl_down(p0, off); p1 += __shfl_down(p1, off); }
    if (t == 0) { out[0] = p0 + bcls[0]; out[1] = p1 + bcls[1]; }
  }
}

extern "C" void kernel_launch(void* const* d_in, const int* in_sizes, int n_in,
                              void* d_out, int out_size, void* d_ws, size_t ws_size,
                              hipStream_t stream) {
  const float* x    = (const float*)d_in[0];
  const float* Wfc  = (const float*)d_in[1];
  const float* bfc  = (const float*)d_in[2];
  const float* Wa   = (const float*)d_in[3];
  const float* ba   = (const float*)d_in[4];
  const float* Wb   = (const float*)d_in[5];
  const float* bb   = (const float*)d_in[6];
  const float* Wc   = (const float*)d_in[7];
  const float* bc   = (const float*)d_in[8];
  const float* Wcls = (const float*)d_in[9];
  const float* bcls = (const float*)d_in[10];
  float* out = (float*)d_out;
  char* ws = (char*)d_ws;

  // workspace layout (bytes)
  unsigned short* xb     = (unsigned short*)(ws + 0);         // 16,777,216
  unsigned short* WfcT   = (unsigned short*)(ws + 16777216);  //  1,048,576
  unsigned short* WabT   = (unsigned short*)(ws + 17825792);  //    524,288
  unsigned short* hbuf   = (unsigned short*)(ws + 18350080);  //  8,388,608
  float*          tbuf   = (float*)(ws + 26738688);           // 16,777,216
  float*          scores = (float*)(ws + 43515904);           //     32,768
  float*          wbuf   = (float*)(ws + 43548672);           //     32,768
  float*          part   = (float*)(ws + 43581440);           //    131,072
  // total ~41.7 MB

  // 1) zero A_raw (custom fill: 16B nontemporal stores)
  zero_out_kernel<<<2048, 256, 0, stream>>>(out);
  // 2) x -> bf16
  conv_x_kernel<<<4096, 256, 0, stream>>>(x, xb);
  // 3) weight transpose+convert
  prep_w_kernel<<<3072, 256, 0, stream>>>(Wfc, Wa, Wb, WfcT, WabT);
  // 4) h = relu(x @ Wfc + bfc), bf16 out
  gemm_bt<0><<<(NROWS / 128) * (HDIM / 64), 256, 0, stream>>>(xb, WfcT, bfc, hbuf, NROWS, HDIM, LDIM);
  // 5) t = h @ [Wa|Wb], f32 out (bias added in score kernel)
  gemm_bt<1><<<(NROWS / 128) * (HDIM / 64), 256, 0, stream>>>(hbuf, WabT, nullptr, tbuf, NROWS, HDIM, HDIM);
  // 6) scores + A_raw diagonal
  score_kernel<<<NROWS / 4, 256, 0, stream>>>(tbuf, ba, bb, Wc, bc, scores, out);
  // 7) softmax closed form -> per-row weights
  reduce_kernel<<<1, 1024, 0, stream>>>(scores, wbuf);
  // 8) weighted column sums (deterministic two-stage)
  wsum_kernel<<<64, 256, 0, stream>>>(hbuf, wbuf, part);
  // 9) M and logits
  final_kernel<<<1, 512, 0, stream>>>(part, Wcls, bcls, out);
}

// Round 3
// 122.713 us; speedup vs baseline: 1.1371x; 1.1371x over previous
//
#include <hip/hip_runtime.h>
#include <stdint.h>

// ---- problem dims ----
#define NROWS 8192
#define LDIM  1024
#define HDIM  512
#define DDIM  256

typedef __attribute__((ext_vector_type(8))) short short8;
typedef __attribute__((ext_vector_type(4))) float f32x4;
typedef __attribute__((ext_vector_type(4))) unsigned int u32x4;

typedef __attribute__((address_space(3))) unsigned int lds_uint;
typedef const __attribute__((address_space(1))) unsigned int glob_uint;

// zero-chunk partition (16B chunks over d_out floats [4, 67108864))
#define ZC_TOTAL 16777215L
#define ZC_MEGA  12582911L
#define ZC_G1    2621440L
#define ZC_G2    1572864L
#define ZB_MEGA  6144   // ceil(ZC_MEGA/2048)
#define ZB_G1    1280   // ZC_G1/2048
#define ZB_G2    768    // ZC_G2/2048

__device__ __forceinline__ void llds16(const void* g, void* l) {
  __builtin_amdgcn_global_load_lds((glob_uint*)g, (lds_uint*)l, 16, 0, 0);
}

__device__ __forceinline__ unsigned short f2bf(float f) {
  union { float f; unsigned int u; } c; c.f = f;
  unsigned int u = c.u;
  unsigned int r = (u + 0x7fffu + ((u >> 16) & 1u)) >> 16;
  return (unsigned short)r;
}

__device__ __forceinline__ float bfbits2f(unsigned int hi16) {
  union { unsigned int u; float f; } c; c.u = hi16;
  return c.f;
}

// zero-duty: block zblk writes chunks [zstart + zblk*2048, min(+2048, zstart+zcount)) of out16
__device__ __forceinline__ void zero_duty(u32x4* __restrict__ out16, long zstart, long zcount,
                                          int zblk, int tid) {
  long b0 = zstart + (long)zblk * 2048;
  long lim = zstart + zcount;
  long b1 = b0 + 2048 < lim ? b0 + 2048 : lim;
  u32x4 z = {0u, 0u, 0u, 0u};
  for (long i = b0 + tid; i < b1; i += 256) out16[i] = z;
}

// ---- mega BW kernel: zero slabs [0,6144) | conv_x [6144,10240) | prep_w [10240,13312) ----
__global__ __launch_bounds__(256) void mega_bw_kernel(const float* __restrict__ x,
                                                      const float* __restrict__ Wfc,
                                                      const float* __restrict__ Wa,
                                                      const float* __restrict__ Wb,
                                                      unsigned short* __restrict__ xb,
                                                      unsigned short* __restrict__ WfcT,
                                                      unsigned short* __restrict__ WabT,
                                                      float* __restrict__ out) {
  const int bid = blockIdx.x;
  const int tid = threadIdx.x;
  if (bid < ZB_MEGA) {
    zero_duty((u32x4*)(out + 4), 0L, ZC_MEGA, bid, tid);
    if (bid == 0 && tid == 0) {
      out[2] = 0.f; out[3] = 0.f;                 // head (before 16B alignment)
      out[67108864] = 0.f; out[67108865] = 0.f;   // tail floats
    }
    return;
  }
  if (bid < ZB_MEGA + 4096) {
    // conv: x f32 -> bf16, 8 elems/thread
    long i = ((long)(bid - ZB_MEGA) * 256 + tid) * 8;
    float4 v0 = *(const float4*)(x + i);
    float4 v1 = *(const float4*)(x + i + 4);
    union { unsigned short s[8]; uint4 u; } o;
    o.s[0] = f2bf(v0.x); o.s[1] = f2bf(v0.y); o.s[2] = f2bf(v0.z); o.s[3] = f2bf(v0.w);
    o.s[4] = f2bf(v1.x); o.s[5] = f2bf(v1.y); o.s[6] = f2bf(v1.z); o.s[7] = f2bf(v1.w);
    *(uint4*)(xb + i) = o.u;
    return;
  }
  // prep_w: transpose + convert
  int idx = (bid - ZB_MEGA - 4096) * 256 + tid;  // 0 .. 786431
  if (idx < 512 * 1024) {
    int n = idx >> 10, k = idx & 1023;
    WfcT[idx] = f2bf(Wfc[k * 512 + n]);
  } else {
    int j = idx - 512 * 1024;
    int n = j >> 9, k = j & 511;
    float v = (n < 256) ? Wa[k * 256 + n] : Wb[k * 256 + (n - 256)];
    WabT[j] = f2bf(v);
  }
}

// ---- bf16 GEMM, A[M][K] x Bt[N][K] -> out[M][N]; tail blocks do zero duty on zout ----
// EPI 0: relu(acc+bias)->bf16 ; EPI 1: raw f32
template <int EPI>
__global__ __launch_bounds__(256) void gemm_bt(const unsigned short* __restrict__ A,
                                               const unsigned short* __restrict__ Bt,
                                               const float* __restrict__ bias,
                                               void* __restrict__ out,
                                               int M, int N, int K,
                                               float* __restrict__ zout, long zstart, long zcount) {
  constexpr int BM = 128, BN = 64, BK = 32;
  __shared__ unsigned short sA[2][BM * BK];
  __shared__ unsigned short sB[2][BN * BK];
  const int tid = threadIdx.x;
  const int nbn = N / BN;
  const int ncomp = (M / BM) * nbn;
  if ((int)blockIdx.x >= ncomp) {
    zero_duty((u32x4*)(zout + 4), zstart, zcount, (int)blockIdx.x - ncomp, tid);
    return;
  }
  const int lane = tid & 63;
  const int wv = tid >> 6;        // wave 0..3
  const int wm = wv >> 1;         // row half
  const int wn = wv & 1;          // col half
  const int bm = blockIdx.x / nbn, bn = blockIdx.x % nbn;
  const int row0 = bm * BM, col0 = bn * BN;

  f32x4 acc[4][2] = {};
  const int nk = K / BK;

  auto stage = [&](int buf, int kt) {
#pragma unroll
    for (int r = 0; r < 2; ++r) {
      int c = r * 256 + tid;
      int arow = c >> 2, acb = (c & 3) * 8;
      const unsigned short* g = A + (long)(row0 + arow) * K + kt * BK + acb;
      unsigned short* l = (unsigned short*)&sA[buf][(r * 256 + wv * 64) * 8];
      llds16(g, l);
    }
    {
      int c = tid;
      int brow = c >> 2, bcb = (c & 3) * 8;
      const unsigned short* g = Bt + (long)(col0 + brow) * K + kt * BK + bcb;
      unsigned short* l = (unsigned short*)&sB[buf][(wv * 64) * 8];
      llds16(g, l);
    }
  };

  stage(0, 0);
  __syncthreads();

  for (int kt = 0; kt < nk; ++kt) {
    int cur = kt & 1;
    if (kt + 1 < nk) stage(cur ^ 1, kt + 1);
    const unsigned short* bA = sA[cur];
    const unsigned short* bB = sB[cur];
    short8 af[4], bfr[2];
#pragma unroll
    for (int fm = 0; fm < 4; ++fm)
      af[fm] = *(const short8*)&bA[(wm * 64 + fm * 16 + (lane & 15)) * BK + (lane >> 4) * 8];
#pragma unroll
    for (int fn = 0; fn < 2; ++fn)
      bfr[fn] = *(const short8*)&bB[(wn * 32 + fn * 16 + (lane & 15)) * BK + (lane >> 4) * 8];
#pragma unroll
    for (int fm = 0; fm < 4; ++fm)
#pragma unroll
      for (int fn = 0; fn < 2; ++fn)
        acc[fm][fn] = __builtin_amdgcn_mfma_f32_16x16x32_bf16(af[fm], bfr[fn], acc[fm][fn], 0, 0, 0);
    __syncthreads();
  }

#pragma unroll
  for (int fm = 0; fm < 4; ++fm) {
#pragma unroll
    for (int fn = 0; fn < 2; ++fn) {
#pragma unroll
      for (int i = 0; i < 4; ++i) {
        int row = row0 + wm * 64 + fm * 16 + (lane >> 4) * 4 + i;
        int col = col0 + wn * 32 + fn * 16 + (lane & 15);
        float v = acc[fm][fn][i];
        if (EPI == 0) {
          v += bias[col];
          v = v > 0.f ? v : 0.f;
          ((unsigned short*)out)[(long)row * N + col] = f2bf(v);
        } else {
          ((float*)out)[(long)row * N + col] = v;
        }
      }
    }
  }
}

// ---- per-row score: s_i = sum_d tanh(t[i][d]+ba[d])*sigmoid(t[i][d+256]+bb[d])*Wc[d] + bc ----
__global__ __launch_bounds__(256) void score_kernel(const float* __restrict__ t,
                                                    const float* __restrict__ ba,
                                                    const float* __restrict__ bb,
                                                    const float* __restrict__ Wc,
                                                    const float* __restrict__ bc,
                                                    float* __restrict__ scores,
                                                    float* __restrict__ out /* d_out base */) {
  int row = blockIdx.x * 4 + (threadIdx.x >> 6);
  int lane = threadIdx.x & 63;
  const float* tr = t + (long)row * 512;
  float s = 0.f;
#pragma unroll
  for (int j = 0; j < 4; ++j) {
    int d = lane + j * 64;
    float u = tr[d] + ba[d];
    float v = tr[d + 256] + bb[d];
    float av = tanhf(u);
    float bv = 1.f / (1.f + __expf(-v));
    s += av * bv * Wc[d];
  }
#pragma unroll
  for (int off = 32; off; off >>= 1) s += __shfl_down(s, off);
  if (lane == 0) {
    float sc = s + bc[0];
    scores[row] = sc;
    out[2 + (long)row * 8193] = sc;  // A_raw diagonal (A_raw starts at flat offset 2)
  }
}

// ---- single-block: m, Z, then w_i = e_i/Z + (n-1)*e0/Z ----
__global__ __launch_bounds__(1024) void reduce_kernel(const float* __restrict__ scores,
                                                      float* __restrict__ w) {
  __shared__ float red[1024];
  int t = threadIdx.x;
  float v[8];
  float mx = -1e30f;
#pragma unroll
  for (int j = 0; j < 8; ++j) { v[j] = scores[t * 8 + j]; mx = fmaxf(mx, v[j]); }
  red[t] = mx; __syncthreads();
  for (int s = 512; s; s >>= 1) { if (t < s) red[t] = fmaxf(red[t], red[t + s]); __syncthreads(); }
  float m = fmaxf(red[0], 0.f);
  __syncthreads();
  float e[8]; float se = 0.f;
#pragma unroll
  for (int j = 0; j < 8; ++j) { e[j] = __expf(v[j] - m); se += e[j]; }
  red[t] = se; __syncthreads();
  for (int s = 512; s; s >>= 1) { if (t < s) red[t] += red[t + s]; __syncthreads(); }
  float e0 = __expf(-m);
  float Z = red[0] + 67100672.0f * e0;  // (n*n - n) * e0
  float c0 = 8191.0f * e0 / Z;          // (n-1)*e0/Z
#pragma unroll
  for (int j = 0; j < 8; ++j) w[t * 8 + j] = e[j] / Z + c0;
}

// ---- partial weighted colsum: part[b][j] = sum_{i in block b} w_i * h[i][j] ----
__global__ __launch_bounds__(256) void wsum_kernel(const unsigned short* __restrict__ h,
                                                   const float* __restrict__ w,
                                                   float* __restrict__ part) {
  int b = blockIdx.x;   // 64 blocks, 128 rows each
  int t = threadIdx.x;  // 256 threads, 2 cols each
  float a0 = 0.f, a1 = 0.f;
  for (int i = b * 128; i < b * 128 + 128; ++i) {
    float wi = w[i];
    unsigned int hv = *(const unsigned int*)&h[(long)i * 512 + t * 2];
    a0 += wi * bfbits2f(hv << 16);
    a1 += wi * bfbits2f(hv & 0xffff0000u);
  }
  part[b * 512 + t * 2] = a0;
  part[b * 512 + t * 2 + 1] = a1;
}

// ---- M[j] = sum_b part[b][j]; logits = M @ Wcls + bcls ----
__global__ __launch_bounds__(512) void final_kernel(const float* __restrict__ part,
                                                    const float* __restrict__ Wcls,
                                                    const float* __restrict__ bcls,
                                                    float* __restrict__ out) {
  __shared__ float Msh[512];
  int t = threadIdx.x;
  float s = 0.f;
  for (int b = 0; b < 64; ++b) s += part[b * 512 + t];
  Msh[t] = s;
  __syncthreads();
  if (t < 64) {
    float p0 = 0.f, p1 = 0.f;
    for (int j = t; j < 512; j += 64) { p0 += Msh[j] * Wcls[j * 2]; p1 += Msh[j] * Wcls[j * 2 + 1]; }
#pragma unroll
    for (int off = 32; off; off >>= 1) { p0 += __shfl_down(p0, off); p1 += __shfl_down(p1, off); }
    if (t == 0) { out[0] = p0 + bcls[0]; out[1] = p1 + bcls[1]; }
  }
}

extern "C" void kernel_launch(void* const* d_in, const int* in_sizes, int n_in,
                              void* d_out, int out_size, void* d_ws, size_t ws_size,
                              hipStream_t stream) {
  const float* x    = (const float*)d_in[0];
  const float* Wfc  = (const float*)d_in[1];
  const float* bfc  = (const float*)d_in[2];
  const float* Wa   = (const float*)d_in[3];
  const float* ba   = (const float*)d_in[4];
  const float* Wb   = (const float*)d_in[5];
  const float* bb   = (const float*)d_in[6];
  const float* Wc   = (const float*)d_in[7];
  const float* bc   = (const float*)d_in[8];
  const float* Wcls = (const float*)d_in[9];
  const float* bcls = (const float*)d_in[10];
  float* out = (float*)d_out;
  char* ws = (char*)d_ws;

  // workspace layout (bytes)
  unsigned short* xb     = (unsigned short*)(ws + 0);         // 16,777,216
  unsigned short* WfcT   = (unsigned short*)(ws + 16777216);  //  1,048,576
  unsigned short* WabT   = (unsigned short*)(ws + 17825792);  //    524,288
  unsigned short* hbuf   = (unsigned short*)(ws + 18350080);  //  8,388,608
  float*          tbuf   = (float*)(ws + 26738688);           // 16,777,216
  float*          scores = (float*)(ws + 43515904);           //     32,768
  float*          wbuf   = (float*)(ws + 43548672);           //     32,768
  float*          part   = (float*)(ws + 43581440);           //    131,072
  // total ~41.7 MB

  // 1) mega BW kernel: 192MB of A_raw zeros + x->bf16 + weight prep
  mega_bw_kernel<<<ZB_MEGA + 4096 + 3072, 256, 0, stream>>>(x, Wfc, Wa, Wb, xb, WfcT, WabT, out);
  // 2) h = relu(x @ Wfc + bfc), bf16 out; tail blocks zero 40MB of A_raw
  gemm_bt<0><<<(NROWS / 128) * (HDIM / 64) + ZB_G1, 256, 0, stream>>>(
      xb, WfcT, bfc, hbuf, NROWS, HDIM, LDIM, out, ZC_MEGA, ZC_G1);
  // 3) t = h @ [Wa|Wb], f32 out; tail blocks zero 24MB of A_raw
  gemm_bt<1><<<(NROWS / 128) * (HDIM / 64) + ZB_G2, 256, 0, stream>>>(
      hbuf, WabT, nullptr, tbuf, NROWS, HDIM, HDIM, out, ZC_MEGA + ZC_G1, ZC_G2);
  // 4) scores + A_raw diagonal
  score_kernel<<<NROWS / 4, 256, 0, stream>>>(tbuf, ba, bb, Wc, bc, scores, out);
  // 5) softmax closed form -> per-row weights
  reduce_kernel<<<1, 1024, 0, stream>>>(scores, wbuf);
  // 6) weighted column sums (deterministic two-stage)
  wsum_kernel<<<64, 256, 0, stream>>>(hbuf, wbuf, part);
  // 7) M and logits
  final_kernel<<<1, 512, 0, stream>>>(part, Wcls, bcls, out);
}

// Round 4
// 117.387 us; speedup vs baseline: 1.1887x; 1.0454x over previous
//
#include <hip/hip_runtime.h>
#include <stdint.h>

// ---- problem dims ----
#define NROWS 8192
#define LDIM  1024
#define HDIM  512

typedef __attribute__((ext_vector_type(8))) short short8;
typedef __attribute__((ext_vector_type(4))) float f32x4;
typedef __attribute__((ext_vector_type(4))) unsigned int u32x4;

typedef __attribute__((address_space(3))) unsigned int lds_uint;
typedef const __attribute__((address_space(1))) unsigned int glob_uint;

// ---- zero partition: 16B chunks over d_out floats [4, 67108864) ----
#define ZN_TOTAL 16777215L
#define Z_MEGA_START 0L
#define Z_MEGA_CNT   6291455L   // 96 MB, 3072 blocks x 2048 chunks
#define ZB_MEGA      3072
#define Z_G1_START   6291455L
#define Z_G1_CNT     5242880L   // 80 MB, 2560 blocks
#define ZB_G1        2560
#define Z_G2_START   11534335L
#define Z_G2_CNT     3670016L   // 56 MB, 1792 blocks
#define ZB_G2        1792
#define Z_SC_START   15204351L  // 24 MB, 768 chunks per score block (2048 blocks)
#define Z_SC_PER     768L

__device__ __forceinline__ void llds16(const void* g, void* l) {
  __builtin_amdgcn_global_load_lds((glob_uint*)g, (lds_uint*)l, 16, 0, 0);
}

__device__ __forceinline__ unsigned short f2bf(float f) {
  union { float f; unsigned int u; } c; c.f = f;
  unsigned int u = c.u;
  unsigned int r = (u + 0x7fffu + ((u >> 16) & 1u)) >> 16;
  return (unsigned short)r;
}

__device__ __forceinline__ float bfbits2f(unsigned int hi16) {
  union { unsigned int u; float f; } c; c.u = hi16;
  return c.f;
}

__device__ __forceinline__ void zero_chunks(u32x4* __restrict__ out16, long c0, long c1, int tid) {
  u32x4 z = {0u, 0u, 0u, 0u};
  for (long i = c0 + tid; i < c1; i += 256) out16[i] = z;
}

// ---- mega BW kernel ----
// blocks [0,3072): zero 96MB | [3072,7168): x->bf16 | [7168,7936): coalesced weight transpose
__global__ __launch_bounds__(256) void mega_bw_kernel(const float* __restrict__ x,
                                                      const float* __restrict__ Wfc,
                                                      const float* __restrict__ Wa,
                                                      const float* __restrict__ Wb,
                                                      unsigned short* __restrict__ xb,
                                                      unsigned short* __restrict__ WfcT,
                                                      unsigned short* __restrict__ WabT,
                                                      float* __restrict__ out) {
  __shared__ float tile[32][33];
  const int bid = blockIdx.x;
  const int tid = threadIdx.x;
  if (bid < ZB_MEGA) {
    long c0 = Z_MEGA_START + (long)bid * 2048;
    long c1 = c0 + 2048 < Z_MEGA_START + Z_MEGA_CNT ? c0 + 2048 : Z_MEGA_START + Z_MEGA_CNT;
    zero_chunks((u32x4*)(out + 4), c0, c1, tid);
    if (bid == 0 && tid == 0) {
      out[2] = 0.f; out[3] = 0.f;                 // head floats (before 16B-aligned region)
      out[67108864] = 0.f; out[67108865] = 0.f;   // tail floats
    }
    return;
  }
  if (bid < ZB_MEGA + 4096) {
    // conv: x f32 -> bf16, 8 elems/thread
    long i = ((long)(bid - ZB_MEGA) * 256 + tid) * 8;
    float4 v0 = *(const float4*)(x + i);
    float4 v1 = *(const float4*)(x + i + 4);
    union { unsigned short s[8]; uint4 u; } o;
    o.s[0] = f2bf(v0.x); o.s[1] = f2bf(v0.y); o.s[2] = f2bf(v0.z); o.s[3] = f2bf(v0.w);
    o.s[4] = f2bf(v1.x); o.s[5] = f2bf(v1.y); o.s[6] = f2bf(v1.z); o.s[7] = f2bf(v1.w);
    *(uint4*)(xb + i) = o.u;
    return;
  }
  // coalesced 32x32 tile transpose + f32->bf16
  int tt = bid - (ZB_MEGA + 4096);  // 0..767
  const float* src; unsigned short* dst; int srcn, dstk, k0, n0;
  if (tt < 512) {          // Wfc [1024][512] -> WfcT [512][1024]
    src = Wfc; dst = WfcT; srcn = 512; dstk = 1024;
    k0 = (tt >> 4) * 32; n0 = (tt & 15) * 32;
  } else if (tt < 640) {   // Wa [512][256] -> WabT rows [0,256)
    int t2 = tt - 512;
    src = Wa; dst = WabT; srcn = 256; dstk = 512;
    k0 = (t2 >> 3) * 32; n0 = (t2 & 7) * 32;
  } else {                 // Wb [512][256] -> WabT rows [256,512)
    int t2 = tt - 640;
    src = Wb; dst = WabT + 256 * 512; srcn = 256; dstk = 512;
    k0 = (t2 >> 3) * 32; n0 = (t2 & 7) * 32;
  }
  int r = tid >> 3, c4 = (tid & 7) * 4;
  float4 v = *(const float4*)(src + (long)(k0 + r) * srcn + n0 + c4);
  tile[r][c4 + 0] = v.x; tile[r][c4 + 1] = v.y; tile[r][c4 + 2] = v.z; tile[r][c4 + 3] = v.w;
  __syncthreads();
  union { unsigned short s[4]; uint2 u; } o;
#pragma unroll
  for (int j = 0; j < 4; ++j) o.s[j] = f2bf(tile[c4 + j][r]);
  *(uint2*)(dst + (long)(n0 + r) * dstk + k0 + c4) = o.u;
}

// ---- bf16 GEMM, 128x128 tile, BK=32, 4 waves (2x2), 4x4 frags/wave ----
// A[M][K] x Bt[N][K] -> out[M][N]; tail blocks do zero duty on zout.
// EPI 0: relu(acc+bias)->bf16 ; EPI 1: raw f32
template <int EPI>
__global__ __launch_bounds__(256) void gemm_bt(const unsigned short* __restrict__ A,
                                               const unsigned short* __restrict__ Bt,
                                               const float* __restrict__ bias,
                                               void* __restrict__ out,
                                               int M, int N, int K,
                                               float* __restrict__ zout, long zstart, long zcount) {
  constexpr int BM = 128, BN = 128, BK = 32;
  __shared__ unsigned short sA[2][BM * BK];
  __shared__ unsigned short sB[2][BN * BK];
  const int tid = threadIdx.x;
  const int nbn = N / BN;
  const int ncomp = (M / BM) * nbn;
  if ((int)blockIdx.x >= ncomp) {
    int zb = (int)blockIdx.x - ncomp;
    long c0 = zstart + (long)zb * 2048;
    long lim = zstart + zcount;
    long c1 = c0 + 2048 < lim ? c0 + 2048 : lim;
    zero_chunks((u32x4*)(zout + 4), c0, c1, tid);
    return;
  }
  const int lane = tid & 63;
  const int wv = tid >> 6;
  const int wm = wv >> 1;
  const int wn = wv & 1;
  const int bm = blockIdx.x / nbn, bn = blockIdx.x % nbn;
  const int row0 = bm * BM, col0 = bn * BN;

  f32x4 acc[4][4] = {};
  const int nk = K / BK;

  auto stage = [&](int buf, int kt) {
    // A tile: 128x32 shorts = 512 16B-chunks, 2 rounds; LDS = linear row-major [128][32]
#pragma unroll
    for (int r = 0; r < 2; ++r) {
      int c = r * 256 + tid;
      int arow = c >> 2, acb = (c & 3) * 8;
      const unsigned short* g = A + (long)(row0 + arow) * K + kt * BK + acb;
      unsigned short* l = (unsigned short*)&sA[buf][(r * 256 + wv * 64) * 8];
      llds16(g, l);
    }
    // B tile: 128x32 shorts, 2 rounds
#pragma unroll
    for (int r = 0; r < 2; ++r) {
      int c = r * 256 + tid;
      int brow = c >> 2, bcb = (c & 3) * 8;
      const unsigned short* g = Bt + (long)(col0 + brow) * K + kt * BK + bcb;
      unsigned short* l = (unsigned short*)&sB[buf][(r * 256 + wv * 64) * 8];
      llds16(g, l);
    }
  };

  stage(0, 0);
  __syncthreads();

  for (int kt = 0; kt < nk; ++kt) {
    int cur = kt & 1;
    if (kt + 1 < nk) stage(cur ^ 1, kt + 1);
    const unsigned short* bA = sA[cur];
    const unsigned short* bB = sB[cur];
    short8 af[4], bfr[4];
#pragma unroll
    for (int fm = 0; fm < 4; ++fm)
      af[fm] = *(const short8*)&bA[(wm * 64 + fm * 16 + (lane & 15)) * BK + (lane >> 4) * 8];
#pragma unroll
    for (int fn = 0; fn < 4; ++fn)
      bfr[fn] = *(const short8*)&bB[(wn * 64 + fn * 16 + (lane & 15)) * BK + (lane >> 4) * 8];
#pragma unroll
    for (int fm = 0; fm < 4; ++fm)
#pragma unroll
      for (int fn = 0; fn < 4; ++fn)
        acc[fm][fn] = __builtin_amdgcn_mfma_f32_16x16x32_bf16(af[fm], bfr[fn], acc[fm][fn], 0, 0, 0);
    __syncthreads();
  }

#pragma unroll
  for (int fm = 0; fm < 4; ++fm) {
#pragma unroll
    for (int fn = 0; fn < 4; ++fn) {
#pragma unroll
      for (int i = 0; i < 4; ++i) {
        int row = row0 + wm * 64 + fm * 16 + (lane >> 4) * 4 + i;
        int col = col0 + wn * 64 + fn * 16 + (lane & 15);
        float v = acc[fm][fn][i];
        if (EPI == 0) {
          v += bias[col];
          v = v > 0.f ? v : 0.f;
          ((unsigned short*)out)[(long)row * N + col] = f2bf(v);
        } else {
          ((float*)out)[(long)row * N + col] = v;
        }
      }
    }
  }
}

// ---- per-row score (+ zero duty); diag write deferred to reduce_kernel ----
__global__ __launch_bounds__(256) void score_kernel(const float* __restrict__ t,
                                                    const float* __restrict__ ba,
                                                    const float* __restrict__ bb,
                                                    const float* __restrict__ Wc,
                                                    const float* __restrict__ bc,
                                                    float* __restrict__ scores,
                                                    float* __restrict__ out /* d_out base */) {
  // zero duty first (stores fire-and-forget)
  {
    long c0 = Z_SC_START + (long)blockIdx.x * Z_SC_PER;
    zero_chunks((u32x4*)(out + 4), c0, c0 + Z_SC_PER, threadIdx.x);
  }
  int row = blockIdx.x * 4 + (threadIdx.x >> 6);
  int lane = threadIdx.x & 63;
  const float* tr = t + (long)row * 512;
  float s = 0.f;
#pragma unroll
  for (int j = 0; j < 4; ++j) {
    int d = lane + j * 64;
    float u = tr[d] + ba[d];
    float v = tr[d + 256] + bb[d];
    float av = tanhf(u);
    float bv = 1.f / (1.f + __expf(-v));
    s += av * bv * Wc[d];
  }
#pragma unroll
  for (int off = 32; off; off >>= 1) s += __shfl_down(s, off);
  if (lane == 0) scores[row] = s + bc[0];
}

// ---- single block: m, Z, weights w_i; also writes A_raw diagonal (after all zeroing done) ----
__global__ __launch_bounds__(1024) void reduce_kernel(const float* __restrict__ scores,
                                                      float* __restrict__ w,
                                                      float* __restrict__ out) {
  __shared__ float red[1024];
  int t = threadIdx.x;
  float v[8];
  float mx = -1e30f;
#pragma unroll
  for (int j = 0; j < 8; ++j) { v[j] = scores[t * 8 + j]; mx = fmaxf(mx, v[j]); }
#pragma unroll
  for (int j = 0; j < 8; ++j) out[2 + 8193L * (t * 8 + j)] = v[j];  // A_raw diagonal
  red[t] = mx; __syncthreads();
  for (int s = 512; s; s >>= 1) { if (t < s) red[t] = fmaxf(red[t], red[t + s]); __syncthreads(); }
  float m = fmaxf(red[0], 0.f);
  __syncthreads();
  float e[8]; float se = 0.f;
#pragma unroll
  for (int j = 0; j < 8; ++j) { e[j] = __expf(v[j] - m); se += e[j]; }
  red[t] = se; __syncthreads();
  for (int s = 512; s; s >>= 1) { if (t < s) red[t] += red[t + s]; __syncthreads(); }
  float e0 = __expf(-m);
  float Z = red[0] + 67100672.0f * e0;  // (n*n - n) * e0
  float c0 = 8191.0f * e0 / Z;          // (n-1)*e0/Z
#pragma unroll
  for (int j = 0; j < 8; ++j) w[t * 8 + j] = e[j] / Z + c0;
}

// ---- partial weighted colsum: part[b][j] = sum_{i in block b} w_i * h[i][j] ----
__global__ __launch_bounds__(256) void wsum_kernel(const unsigned short* __restrict__ h,
                                                   const float* __restrict__ w,
                                                   float* __restrict__ part) {
  int b = blockIdx.x;   // 64 blocks, 128 rows each
  int t = threadIdx.x;  // 256 threads, 2 cols each
  float a0 = 0.f, a1 = 0.f;
  for (int i = b * 128; i < b * 128 + 128; ++i) {
    float wi = w[i];
    unsigned int hv = *(const unsigned int*)&h[(long)i * 512 + t * 2];
    a0 += wi * bfbits2f(hv << 16);
    a1 += wi * bfbits2f(hv & 0xffff0000u);
  }
  part[b * 512 + t * 2] = a0;
  part[b * 512 + t * 2 + 1] = a1;
}

// ---- M[j] = sum_b part[b][j]; logits = M @ Wcls + bcls ----
__global__ __launch_bounds__(512) void final_kernel(const float* __restrict__ part,
                                                    const float* __restrict__ Wcls,
                                                    const float* __restrict__ bcls,
                                                    float* __restrict__ out) {
  __shared__ float Msh[512];
  int t = threadIdx.x;
  float s = 0.f;
  for (int b = 0; b < 64; ++b) s += part[b * 512 + t];
  Msh[t] = s;
  __syncthreads();
  if (t < 64) {
    float p0 = 0.f, p1 = 0.f;
    for (int j = t; j < 512; j += 64) { p0 += Msh[j] * Wcls[j * 2]; p1 += Msh[j] * Wcls[j * 2 + 1]; }
#pragma unroll
    for (int off = 32; off; off >>= 1) { p0 += __shfl_down(p0, off); p1 += __shfl_down(p1, off); }
    if (t == 0) { out[0] = p0 + bcls[0]; out[1] = p1 + bcls[1]; }
  }
}

extern "C" void kernel_launch(void* const* d_in, const int* in_sizes, int n_in,
                              void* d_out, int out_size, void* d_ws, size_t ws_size,
                              hipStream_t stream) {
  const float* x    = (const float*)d_in[0];
  const float* Wfc  = (const float*)d_in[1];
  const float* bfc  = (const float*)d_in[2];
  const float* Wa   = (const float*)d_in[3];
  const float* ba   = (const float*)d_in[4];
  const float* Wb   = (const float*)d_in[5];
  const float* bb   = (const float*)d_in[6];
  const float* Wc   = (const float*)d_in[7];
  const float* bc   = (const float*)d_in[8];
  const float* Wcls = (const float*)d_in[9];
  const float* bcls = (const float*)d_in[10];
  float* out = (float*)d_out;
  char* ws = (char*)d_ws;

  // workspace layout (bytes)
  unsigned short* xb     = (unsigned short*)(ws + 0);         // 16,777,216
  unsigned short* WfcT   = (unsigned short*)(ws + 16777216);  //  1,048,576
  unsigned short* WabT   = (unsigned short*)(ws + 17825792);  //    524,288
  unsigned short* hbuf   = (unsigned short*)(ws + 18350080);  //  8,388,608
  float*          tbuf   = (float*)(ws + 26738688);           // 16,777,216
  float*          scores = (float*)(ws + 43515904);           //     32,768
  float*          wbuf   = (float*)(ws + 43548672);           //     32,768
  float*          part   = (float*)(ws + 43581440);           //    131,072

  // 1) mega BW kernel: 96MB zeros + x->bf16 + coalesced weight transpose
  mega_bw_kernel<<<ZB_MEGA + 4096 + 768, 256, 0, stream>>>(x, Wfc, Wa, Wb, xb, WfcT, WabT, out);
  // 2) h = relu(x @ Wfc + bfc); tail blocks zero 80MB
  gemm_bt<0><<<(NROWS / 128) * (HDIM / 128) + ZB_G1, 256, 0, stream>>>(
      xb, WfcT, bfc, hbuf, NROWS, HDIM, LDIM, out, Z_G1_START, Z_G1_CNT);
  // 3) t = h @ [Wa|Wb] (f32); tail blocks zero 56MB
  gemm_bt<1><<<(NROWS / 128) * (HDIM / 128) + ZB_G2, 256, 0, stream>>>(
      hbuf, WabT, nullptr, tbuf, NROWS, HDIM, HDIM, out, Z_G2_START, Z_G2_CNT);
  // 4) scores (+ 24MB zero duty)
  score_kernel<<<NROWS / 4, 256, 0, stream>>>(tbuf, ba, bb, Wc, bc, scores, out);
  // 5) softmax closed form -> weights; writes A_raw diagonal
  reduce_kernel<<<1, 1024, 0, stream>>>(scores, wbuf, out);
  // 6) weighted column sums
  wsum_kernel<<<64, 256, 0, stream>>>(hbuf, wbuf, part);
  // 7) M and logits
  final_kernel<<<1, 512, 0, stream>>>(part, Wcls, bcls, out);
}